// Round 1
// 20534.207 us; speedup vs baseline: 1.0357x; 1.0357x over previous
//
#include <hip/hip_runtime.h>
#include <math.h>

#define BB 16
#define SS 32
#define DIN 8
#define DD 512
#define DOUTC 8
#define LLAYERS 4
#define HH 8
#define DFF 2048
#define DHH 64
#define TT 31      // positions produced (S-1)
#define NWG 64     // persistent grid: 64 WGs x 256 threads, co-resident on 256 CUs
#define PS 520     // padded row stride for [16][512] LDS tiles (breaks bank conflicts)
#define PSF 260    // padded row stride for [16][256] f1 chunk

struct P {
  const float *seq,*pe,*Wt,*bt,*Wq,*bq,*Wk,*bk,*Wv,*bv,*Wo,*bo,
              *ln1s,*ln1b,*W1,*b1,*W2,*b2,*ln2s,*ln2b,*Wf,*bf;
  float *Kc,*Vc,*ctx,*sA,*sB,*f1,*xbuf,*ybuf,*out;
  unsigned *bar;
};

// ---------------------------------------------------------------------------
// Device-scope grid barrier: single monotonic counter, target grows by NWG
// per barrier. RELEASE on arrive (wb L2), ACQUIRE fence on exit (inv L1/L2)
// -> cross-XCD visibility of all prior plain stores (G16).
// Counter is reset to 0 by hipMemsetAsync before each launch (graph-safe).
// ---------------------------------------------------------------------------
__device__ __forceinline__ void gbar(unsigned* bar, unsigned tgt) {
  __syncthreads();
  if (threadIdx.x == 0) {
    __hip_atomic_fetch_add(bar, 1u, __ATOMIC_RELEASE, __HIP_MEMORY_SCOPE_AGENT);
    while (__hip_atomic_load(bar, __ATOMIC_RELAXED, __HIP_MEMORY_SCOPE_AGENT) < tgt)
      __builtin_amdgcn_s_sleep(2);
    __builtin_amdgcn_fence(__ATOMIC_ACQUIRE, "agent");
  }
  __syncthreads();
}

// ---------------------------------------------------------------------------
// HEAD: out[b][p-1] = LN2_3(sB[b]) @ Wf + bf ; feedback y -> ybuf.
// Called with p in [1..31]; p==31 writes the final row (ybuf write harmless).
// wg<16 (one WG per batch), single wave. No __syncthreads inside.
// ---------------------------------------------------------------------------
__device__ __forceinline__ void head_stage(const P& prm, int p) {
  const int wg = blockIdx.x, t = threadIdx.x;
  if (wg >= BB || t >= 64) return;
  const int b = wg;
  float v[8]; float s = 0.f, q = 0.f;
#pragma unroll
  for (int j = 0; j < 8; j++) {
    float x = prm.sB[b * DD + t + j * 64];
    v[j] = x; s += x; q += x * x;
  }
#pragma unroll
  for (int m = 32; m >= 1; m >>= 1) { s += __shfl_xor(s, m); q += __shfl_xor(q, m); }
  const float mu = s * (1.f / DD);
  const float rs = rsqrtf(fmaxf(q * (1.f / DD) - mu * mu, 0.f) + 1e-5f);
  const float* g  = prm.ln2s + 3 * DD;
  const float* be = prm.ln2b + 3 * DD;
  float po[8];
#pragma unroll
  for (int oc = 0; oc < 8; oc++) po[oc] = 0.f;
#pragma unroll
  for (int j = 0; j < 8; j++) {
    const int i = t + j * 64;
    const float x = (v[j] - mu) * rs * g[i] + be[i];
#pragma unroll
    for (int oc = 0; oc < 8; oc++) po[oc] += x * prm.Wf[i * DOUTC + oc];
  }
#pragma unroll
  for (int m = 32; m >= 1; m >>= 1) {
#pragma unroll
    for (int oc = 0; oc < 8; oc++) po[oc] += __shfl_xor(po[oc], m);
  }
  if (t < 8) {
    const int oc = t;
    const float y = po[oc] + prm.bf[oc];
    prm.ybuf[b * DOUTC + oc] = y;
    prm.out[((size_t)b * TT + (p - 1)) * DOUTC + oc] = y;
  }
}

// ---------------------------------------------------------------------------
// QKV + attention, fused. wg<32: h = wg>>2, batch-quad bg = wg&3.
// Builds x rows (LN2 of sB, or embedding) in LDS; h==0 WGs publish x to xbuf
// (residual for O-proj). KV-cache rows of a given (b,h) are touched by the
// SAME block every step -> stay in that XCD's L2.
// ---------------------------------------------------------------------------
__device__ __forceinline__ void qkv_stage(const P& prm, int p, int l, float* sh,
                                          float (*qs)[DHH], float (*as4)[32],
                                          float (*mvv)[2], float (*yl)[8]) {
  const int wg = blockIdx.x, t = threadIdx.x;
  if (wg >= 32) return;
  const int h = wg >> 2, bg = wg & 3, b0 = bg * 4;

  // ---- build x rows for batches b0..b0+3 into sh[0..4*PS)
  if (l > 0) {
    for (int idx = t; idx < 4 * DD; idx += 256) {
      int r = idx >> 9, i = idx & 511;
      sh[r * PS + i] = prm.sB[(size_t)(b0 + r) * DD + i];
    }
    __syncthreads();
    {
      int r = t >> 6, sub = t & 63;
      float s = 0.f, q = 0.f;
      for (int i = sub; i < DD; i += 64) { float v = sh[r * PS + i]; s += v; q += v * v; }
#pragma unroll
      for (int m = 32; m >= 1; m >>= 1) { s += __shfl_xor(s, m); q += __shfl_xor(q, m); }
      if (sub == 0) {
        float mu = s * (1.f / DD);
        mvv[r][0] = mu;
        mvv[r][1] = rsqrtf(fmaxf(q * (1.f / DD) - mu * mu, 0.f) + 1e-5f);
      }
    }
    __syncthreads();
    const float* g  = prm.ln2s + (l - 1) * DD;
    const float* be = prm.ln2b + (l - 1) * DD;
    for (int idx = t; idx < 4 * DD; idx += 256) {
      int r = idx >> 9, i = idx & 511;
      sh[r * PS + i] = (sh[r * PS + i] - mvv[r][0]) * mvv[r][1] * g[i] + be[i];
    }
    __syncthreads();
  } else {
    if (t < 32) {
      int r = t >> 3, k = t & 7;
      yl[r][k] = (p == 0) ? prm.seq[(size_t)(b0 + r) * SS * DIN + k]
                          : prm.ybuf[(b0 + r) * DOUTC + k];
    }
    __syncthreads();
    for (int idx = t; idx < 4 * DD; idx += 256) {
      int r = idx >> 9, i = idx & 511;
      float a = prm.bt[i] + prm.pe[(size_t)p * DD + i];
#pragma unroll
      for (int k = 0; k < 8; k++) a += yl[r][k] * prm.Wt[k * DD + i];
      sh[r * PS + i] = a;
    }
    __syncthreads();
  }

  // publish x rows (attention residual) once
  if (h == 0) {
    for (int idx = t; idx < 4 * DD; idx += 256) {
      int r = idx >> 9, i = idx & 511;
      prm.xbuf[(size_t)(b0 + r) * DD + i] = sh[r * PS + i];
    }
  }

  // ---- q,k,v: 192 threads = 3 mats x 64 dims, 4 batches per thread
  if (t < 192) {
    const int mat = t >> 6, d = t & 63, col = h * DHH + d;
    const float* W = (mat == 0 ? prm.Wq : (mat == 1 ? prm.Wk : prm.Wv)) + (size_t)l * DD * DD;
    const float bias = (mat == 0 ? prm.bq : (mat == 1 ? prm.bk : prm.bv))[l * DD + col];
    float a0 = bias, a1 = bias, a2 = bias, a3 = bias;
    for (int i = 0; i < DD; i += 4) {
      float4 x0 = *(const float4*)&sh[0 * PS + i];
      float4 x1 = *(const float4*)&sh[1 * PS + i];
      float4 x2 = *(const float4*)&sh[2 * PS + i];
      float4 x3 = *(const float4*)&sh[3 * PS + i];
      float w0 = W[(size_t)(i + 0) * DD + col];
      float w1 = W[(size_t)(i + 1) * DD + col];
      float w2 = W[(size_t)(i + 2) * DD + col];
      float w3 = W[(size_t)(i + 3) * DD + col];
      a0 += x0.x * w0 + x0.y * w1 + x0.z * w2 + x0.w * w3;
      a1 += x1.x * w0 + x1.y * w1 + x1.z * w2 + x1.w * w3;
      a2 += x2.x * w0 + x2.y * w1 + x2.z * w2 + x2.w * w3;
      a3 += x3.x * w0 + x3.y * w1 + x3.z * w2 + x3.w * w3;
    }
    if (mat == 0) {
      qs[0][d] = a0; qs[1][d] = a1; qs[2][d] = a2; qs[3][d] = a3;
    } else {
      float* dst = (mat == 1) ? prm.Kc : prm.Vc;
      size_t base = ((size_t)(l * BB + b0) * TT + p) * DD + col;
      const size_t st = (size_t)TT * DD;
      dst[base] = a0; dst[base + st] = a1; dst[base + 2 * st] = a2; dst[base + 3 * st] = a3;
    }
  }
  __syncthreads();

  // ---- scores + softmax (wave r = batch b0+r, lane = key pos j)
  {
    int r = t >> 6, lane = t & 63, b = b0 + r;
    float sc = -1e30f;
    if (lane <= p) {
      const float* kr = prm.Kc + ((size_t)(l * BB + b) * TT + lane) * DD + h * DHH;
      float s = 0.f;
#pragma unroll 16
      for (int d = 0; d < DHH; d++) s += qs[r][d] * kr[d];
      sc = s * 0.125f;  // 1/sqrt(64)
    }
    float mx = sc;
#pragma unroll
    for (int m = 16; m >= 1; m >>= 1) mx = fmaxf(mx, __shfl_xor(mx, m));
    float e = (lane <= p) ? __expf(sc - mx) : 0.f;
    float den = e;
#pragma unroll
    for (int m = 16; m >= 1; m >>= 1) den += __shfl_xor(den, m);
    if (lane < 32) as4[r][lane] = (lane <= p) ? (e / den) : 0.f;
  }
  __syncthreads();

  // ---- ctx = attn @ V (wave r = batch, lane = head dim d)
  {
    int r = t >> 6, d = t & 63, b = b0 + r;
    const float* vbase = prm.Vc + ((size_t)(l * BB + b) * TT) * DD + h * DHH + d;
    float a = 0.f;
    for (int j = 0; j <= p; j++) a += as4[r][j] * vbase[(size_t)j * DD];
    prm.ctx[(size_t)b * DD + h * DHH + d] = a;
  }
}

// ---------------------------------------------------------------------------
// O-proj + residual: sA = xbuf + ctx@Wo + bo. wg<32, 16 cols per WG.
// ---------------------------------------------------------------------------
__device__ __forceinline__ void oproj_stage(const P& prm, int l, float* sh) {
  const int wg = blockIdx.x, t = threadIdx.x;
  if (wg >= 32) return;
  for (int idx = t; idx < BB * DD; idx += 256) {
    int b = idx >> 9, i = idx & 511;
    sh[b * PS + i] = prm.ctx[idx];
  }
  __syncthreads();
  const int b = t >> 4, ci = t & 15, c = wg * 16 + ci;
  const float* wo = prm.Wo + (size_t)l * DD * DD;
  float a = prm.bo[l * DD + c];
  for (int i = 0; i < DD; i += 4) {
    float4 x = *(const float4*)&sh[b * PS + i];
    float w0 = wo[(size_t)(i + 0) * DD + c];
    float w1 = wo[(size_t)(i + 1) * DD + c];
    float w2 = wo[(size_t)(i + 2) * DD + c];
    float w3 = wo[(size_t)(i + 3) * DD + c];
    a += x.x * w0 + x.y * w1 + x.z * w2 + x.w * w3;
  }
  prm.sA[(size_t)b * DD + c] = prm.xbuf[(size_t)b * DD + c] + a;
}

// ---------------------------------------------------------------------------
// FFN1: f1 = relu(LN1(sA) @ W1 + b1). All 64 WGs, 32 cols each.
// Also publishes LN1(sA) to xbuf (FFN2 residual) and zeroes sB for FFN2's
// split-K atomic accumulation.
// ---------------------------------------------------------------------------
__device__ __forceinline__ void ffn1_stage(const P& prm, int l, float* sh,
                                           float (*mvv)[2]) {
  const int wg = blockIdx.x, t = threadIdx.x;
  for (int idx = t; idx < BB * DD; idx += 256) {
    int r = idx >> 9, i = idx & 511;
    sh[r * PS + i] = prm.sA[idx];
  }
  __syncthreads();
  {
    int r = t >> 4, sub = t & 15;
    float s = 0.f, q = 0.f;
    for (int i = sub; i < DD; i += 16) { float v = sh[r * PS + i]; s += v; q += v * v; }
#pragma unroll
    for (int m = 8; m >= 1; m >>= 1) { s += __shfl_xor(s, m); q += __shfl_xor(q, m); }
    if (sub == 0) {
      float mu = s * (1.f / DD);
      mvv[r][0] = mu;
      mvv[r][1] = rsqrtf(fmaxf(q * (1.f / DD) - mu * mu, 0.f) + 1e-5f);
    }
  }
  __syncthreads();
  const float* g  = prm.ln1s + l * DD;
  const float* be = prm.ln1b + l * DD;
  for (int idx = t; idx < BB * DD; idx += 256) {
    int r = idx >> 9, i = idx & 511;
    sh[r * PS + i] = (sh[r * PS + i] - mvv[r][0]) * mvv[r][1] * g[i] + be[i];
  }
  __syncthreads();
  if (wg < BB) {
    for (int i = t; i < DD; i += 256) {
      prm.xbuf[(size_t)wg * DD + i] = sh[wg * PS + i];
      prm.sB[(size_t)wg * DD + i] = 0.f;
    }
  }
  {
    const int ci = t & 31, bq = t >> 5;           // bq in [0,8)
    const int c = wg * 32 + ci;
    const int bA = bq * 2, bC = bq * 2 + 1;
    const float* w1 = prm.W1 + (size_t)l * DD * DFF;
    float a0 = prm.b1[l * DFF + c], a1 = a0;
    for (int i = 0; i < DD; i += 4) {
      float4 xA = *(const float4*)&sh[bA * PS + i];
      float4 xC = *(const float4*)&sh[bC * PS + i];
      float w0 = w1[(size_t)(i + 0) * DFF + c];
      float w1v = w1[(size_t)(i + 1) * DFF + c];
      float w2 = w1[(size_t)(i + 2) * DFF + c];
      float w3 = w1[(size_t)(i + 3) * DFF + c];
      a0 += xA.x * w0 + xA.y * w1v + xA.z * w2 + xA.w * w3;
      a1 += xC.x * w0 + xC.y * w1v + xC.z * w2 + xC.w * w3;
    }
    prm.f1[(size_t)bA * DFF + c] = fmaxf(a0, 0.f);
    prm.f1[(size_t)bC * DFF + c] = fmaxf(a1, 0.f);
  }
}

// ---------------------------------------------------------------------------
// FFN2 split-K: sB += chunk(f1) @ chunk(W2); kq==0 also adds LN1-residual+b2.
// 64 WGs = 8 K-chunks (kq, 256 each) x 8 col-groups (cg, 64 cols).
// ---------------------------------------------------------------------------
__device__ __forceinline__ void ffn2_stage(const P& prm, int l, float* sh) {
  const int wg = blockIdx.x, t = threadIdx.x;
  const int kq = wg & 7, cg = wg >> 3;
  for (int idx = t; idx < BB * 256; idx += 256) {
    int b = idx >> 8, i = idx & 255;
    sh[b * PSF + i] = prm.f1[(size_t)b * DFF + kq * 256 + i];
  }
  __syncthreads();
  const int c = cg * 64 + (t & 63), bq = t >> 6;  // bq in [0,4)
  const int b0 = bq * 4;
  const float* w2 = prm.W2 + (size_t)l * DFF * DD;
  float acc0 = 0.f, acc1 = 0.f, acc2 = 0.f, acc3 = 0.f;
  for (int i = 0; i < 256; i += 4) {
    float4 f0 = *(const float4*)&sh[(b0 + 0) * PSF + i];
    float4 f1v = *(const float4*)&sh[(b0 + 1) * PSF + i];
    float4 f2 = *(const float4*)&sh[(b0 + 2) * PSF + i];
    float4 f3 = *(const float4*)&sh[(b0 + 3) * PSF + i];
    float w0 = w2[(size_t)(kq * 256 + i + 0) * DD + c];
    float w1 = w2[(size_t)(kq * 256 + i + 1) * DD + c];
    float w2v = w2[(size_t)(kq * 256 + i + 2) * DD + c];
    float w3 = w2[(size_t)(kq * 256 + i + 3) * DD + c];
    acc0 += f0.x * w0 + f0.y * w1 + f0.z * w2v + f0.w * w3;
    acc1 += f1v.x * w0 + f1v.y * w1 + f1v.z * w2v + f1v.w * w3;
    acc2 += f2.x * w0 + f2.y * w1 + f2.z * w2v + f2.w * w3;
    acc3 += f3.x * w0 + f3.y * w1 + f3.z * w2v + f3.w * w3;
  }
  const float b2v = prm.b2[l * DD + c];
  float adds[4] = {acc0, acc1, acc2, acc3};
#pragma unroll
  for (int rr = 0; rr < 4; rr++) {
    const int b = b0 + rr;
    float add = adds[rr];
    if (kq == 0) add += prm.xbuf[(size_t)b * DD + c] + b2v;
    atomicAdd(&prm.sB[(size_t)b * DD + c], add);
  }
}

// ---------------------------------------------------------------------------
__global__ void __launch_bounds__(256, 1) k_all(P prm) {
  __shared__ __align__(16) float sh[BB * PS];   // 33.3 KB
  __shared__ float qs[4][DHH];
  __shared__ float as4[4][32];
  __shared__ float mvv[BB][2];
  __shared__ float yl[4][8];
  unsigned tgt = 0;
  for (int p = 0; p < TT; p++) {
    if (p > 0) {
      head_stage(prm, p);
      tgt += NWG; gbar(prm.bar, tgt);
    }
    for (int l = 0; l < LLAYERS; l++) {
      qkv_stage(prm, p, l, sh, qs, as4, mvv, yl);
      tgt += NWG; gbar(prm.bar, tgt);
      oproj_stage(prm, l, sh);
      tgt += NWG; gbar(prm.bar, tgt);
      ffn1_stage(prm, l, sh, mvv);
      tgt += NWG; gbar(prm.bar, tgt);
      ffn2_stage(prm, l, sh);
      tgt += NWG; gbar(prm.bar, tgt);
    }
  }
  head_stage(prm, TT);  // final row (p-1 == 30)
}

// ---------------------------------------------------------------------------
extern "C" void kernel_launch(void* const* d_in, const int* in_sizes, int n_in,
                              void* d_out, int out_size, void* d_ws, size_t ws_size,
                              hipStream_t stream) {
  (void)in_sizes; (void)n_in; (void)out_size; (void)ws_size;
  P prm;
  prm.seq  = (const float*)d_in[0];
  prm.pe   = (const float*)d_in[1];
  prm.Wt   = (const float*)d_in[2];
  prm.bt   = (const float*)d_in[3];
  prm.Wq   = (const float*)d_in[4];
  prm.bq   = (const float*)d_in[5];
  prm.Wk   = (const float*)d_in[6];
  prm.bk   = (const float*)d_in[7];
  prm.Wv   = (const float*)d_in[8];
  prm.bv   = (const float*)d_in[9];
  prm.Wo   = (const float*)d_in[10];
  prm.bo   = (const float*)d_in[11];
  prm.ln1s = (const float*)d_in[12];
  prm.ln1b = (const float*)d_in[13];
  prm.W1   = (const float*)d_in[14];
  prm.b1   = (const float*)d_in[15];
  prm.W2   = (const float*)d_in[16];
  prm.b2   = (const float*)d_in[17];
  prm.ln2s = (const float*)d_in[18];
  prm.ln2b = (const float*)d_in[19];
  prm.Wf   = (const float*)d_in[20];
  prm.bf   = (const float*)d_in[21];

  float* ws = (float*)d_ws;
  const size_t KSZ = (size_t)LLAYERS * BB * TT * DD;
  prm.Kc   = ws;
  prm.Vc   = ws + KSZ;
  prm.ctx  = ws + 2 * KSZ;
  prm.sA   = prm.ctx + (size_t)BB * DD;
  prm.sB   = prm.sA + (size_t)BB * DD;
  prm.f1   = prm.sB + (size_t)BB * DD;
  prm.xbuf = prm.f1 + (size_t)BB * DFF;
  prm.ybuf = prm.xbuf + (size_t)BB * DD;
  prm.bar  = (unsigned*)(prm.ybuf + BB * DOUTC);
  prm.out  = (float*)d_out;

  hipMemsetAsync((void*)prm.bar, 0, 64, stream);
  hipLaunchKernelGGL(k_all, dim3(NWG), dim3(256), 0, stream, prm);
}

// Round 2
// 8893.594 us; speedup vs baseline: 2.3913x; 2.3089x over previous
//
#include <hip/hip_runtime.h>
#include <math.h>

#define BB 16
#define SS 32
#define DIN 8
#define DD 512
#define DOUTC 8
#define LLAYERS 4
#define HH 8
#define DFF 2048
#define DHH 64
#define TT 31       // positions produced (S-1)
#define NWG 256     // persistent grid: 256 WGs x 256 threads (1/CU)
#define XP 520      // padded stride for [4][512] LDS rows (520&31=8, float4-aligned)
#define XP2 264     // padded stride for [4][256]
#define KLS 65      // LDS row stride for attn K/V tiles (65&31=1 -> conflict-free)

struct P {
  const float *seq,*pe,*Wt,*bt,*Wq,*bq,*Wk,*bk,*Wv,*bv,*Wo,*bo,
              *ln1s,*ln1b,*W1,*b1,*W2,*b2,*ln2s,*ln2b,*Wf,*bf;
  float *Kc,*Vc,*qkvp,*pg,*ctx,*xbuf,*ln1x,*sB,*f1,*out;
  unsigned *bar;
};

#define KVIDX(l,b,j) ((((size_t)((l)*BB+(b)))*TT + (j)) * DD)

// ---------------------------------------------------------------------------
// Device-scope grid barrier (single monotonic counter; reset by memset/launch)
// ---------------------------------------------------------------------------
__device__ __forceinline__ void gbar(unsigned* bar, unsigned tgt) {
  __syncthreads();
  if (threadIdx.x == 0) {
    __hip_atomic_fetch_add(bar, 1u, __ATOMIC_RELEASE, __HIP_MEMORY_SCOPE_AGENT);
    while (__hip_atomic_load(bar, __ATOMIC_RELAXED, __HIP_MEMORY_SCOPE_AGENT) < tgt)
      __builtin_amdgcn_s_sleep(2);
    __builtin_amdgcn_fence(__ATOMIC_ACQUIRE, "agent");
  }
  __syncthreads();
}

// ---------------------------------------------------------------------------
// LN stats helper: X holds 4 rows at stride XP; wave r -> row r. MV[r*2]=mu,
// MV[r*2+1]=rsigma. Caller syncs.
// ---------------------------------------------------------------------------
__device__ __forceinline__ void ln_stats4(const float* X, float* MV, int t) {
  int r = t >> 6, ln = t & 63;
  float s = 0.f, q = 0.f;
  for (int i = ln; i < DD; i += 64) { float v = X[r*XP + i]; s += v; q += v*v; }
#pragma unroll
  for (int m = 32; m >= 1; m >>= 1) { s += __shfl_xor(s, m); q += __shfl_xor(q, m); }
  if (ln == 0) {
    float mu = s * (1.f/DD);
    MV[r*2]   = mu;
    MV[r*2+1] = rsqrtf(fmaxf(q * (1.f/DD) - mu*mu, 0.f) + 1e-5f);
  }
}

// ---------------------------------------------------------------------------
// PROJ: partials of x@{Wq|Wk|Wv} -> qkvp[kg][b][1536]. 192 WGs =
// cb(24: mat*8+colblk) x mb(4: 4 batches) x kg(2: K-half). Also builds x
// (LN2 of sB, or head+embed for l==0), publishes xbuf, out row (l==0,p>0).
// ---------------------------------------------------------------------------
__device__ __forceinline__ void proj_stage(const P& prm, int p, int l, float* SH) {
  const int wg = blockIdx.x, t = threadIdx.x;
  if (wg >= 192) return;
  const int kg = wg & 1, mb = (wg >> 1) & 3, cb = wg >> 3;
  const int b0 = mb * 4;
  float* X   = SH;              // 4*XP
  float* RED = SH + 4*XP;       // 1024
  float* YP  = RED + 1024;      // 256
  float* YS  = YP + 256;        // 32
  float* MV  = YS + 32;         // 8

  if (l > 0 || p > 0) {
    for (int idx = t; idx < 4*DD; idx += 256) {
      int r = idx >> 9, i = idx & 511;
      X[r*XP + i] = prm.sB[(size_t)(b0+r)*DD + i];
    }
    __syncthreads();
    ln_stats4(X, MV, t);
    __syncthreads();
    const int pl = (l > 0) ? (l - 1) : 3;
    const float* g  = prm.ln2s + pl*DD;
    const float* be = prm.ln2b + pl*DD;
    for (int idx = t; idx < 4*DD; idx += 256) {
      int r = idx >> 9, i = idx & 511;
      X[r*XP + i] = (X[r*XP + i] - MV[r*2]) * MV[r*2+1] * g[i] + be[i];
    }
    __syncthreads();
  }
  if (l == 0) {
    if (p == 0) {
      if (t < 32) { int r = t>>3, c = t&7; YS[r*8 + c] = prm.seq[(size_t)(b0+r)*SS*DIN + c]; }
      __syncthreads();
    } else {
      { // y = LN2_3(sB) @ Wf + bf  (X currently holds LN'd rows)
        int r = t >> 6, oc = (t >> 3) & 7, ks = t & 7;
        float a = 0.f;
        const float* xr = X + r*XP + ks*64;
        for (int i = 0; i < 64; i++) a += xr[i] * prm.Wf[(ks*64 + i)*DOUTC + oc];
        YP[t] = a;
      }
      __syncthreads();
      if (t < 32) {
        int r = t>>3, oc = t&7;
        float yv = prm.bf[oc];
#pragma unroll
        for (int k = 0; k < 8; k++) yv += YP[r*64 + oc*8 + k];
        YS[r*8 + oc] = yv;
        if (cb == 0 && kg == 0)
          prm.out[((size_t)(b0+r)*TT + (p-1))*DOUTC + oc] = yv;
      }
      __syncthreads();
    }
    // embed: x = y@Wt + bt + pe[p]
    for (int idx = t; idx < 4*DD; idx += 256) {
      int r = idx >> 9, i = idx & 511;
      float a = prm.bt[i] + prm.pe[(size_t)p*DD + i];
#pragma unroll
      for (int k = 0; k < 8; k++) a += YS[r*8 + k] * prm.Wt[k*DD + i];
      X[r*XP + i] = a;
    }
    __syncthreads();
  }
  if (cb == 0 && kg == 0) {  // publish layer input (oproj residual)
    for (int idx = t; idx < 4*DD; idx += 256) {
      int r = idx >> 9, i = idx & 511;
      prm.xbuf[(size_t)(b0+r)*DD + i] = X[r*XP + i];
    }
  }
  // GEMM partial: wave w covers K sub-slice, 64 cols, 4 batches
  {
    const int w = t >> 6, lane = t & 63;
    const int k0 = kg*256 + w*64;
    const int mat = cb >> 3;
    const int cl = (cb & 7)*64 + lane;
    const float* W = ((mat == 0) ? prm.Wq : (mat == 1) ? prm.Wk : prm.Wv) + (size_t)l*DD*DD;
    const float* wp = W + (size_t)k0*DD + cl;
    float a0 = 0.f, a1 = 0.f, a2 = 0.f, a3 = 0.f;
    for (int kk = 0; kk < 64; kk += 4) {
      float4 x0 = *(const float4*)&X[0*XP + k0 + kk];
      float4 x1 = *(const float4*)&X[1*XP + k0 + kk];
      float4 x2 = *(const float4*)&X[2*XP + k0 + kk];
      float4 x3 = *(const float4*)&X[3*XP + k0 + kk];
      float w0 = wp[0], w1 = wp[DD], w2 = wp[2*DD], w3 = wp[3*DD];
      wp += 4*DD;
      a0 += x0.x*w0 + x0.y*w1 + x0.z*w2 + x0.w*w3;
      a1 += x1.x*w0 + x1.y*w1 + x1.z*w2 + x1.w*w3;
      a2 += x2.x*w0 + x2.y*w1 + x2.z*w2 + x2.w*w3;
      a3 += x3.x*w0 + x3.y*w1 + x3.z*w2 + x3.w*w3;
    }
    RED[w*256 +   0 + lane] = a0;
    RED[w*256 +  64 + lane] = a1;
    RED[w*256 + 128 + lane] = a2;
    RED[w*256 + 192 + lane] = a3;
  }
  __syncthreads();
  {
    int m = t >> 6, lane = t & 63;
    float v = RED[0 + m*64 + lane] + RED[256 + m*64 + lane]
            + RED[512 + m*64 + lane] + RED[768 + m*64 + lane];
    const int mat = cb >> 3;
    prm.qkvp[(size_t)kg*(BB*1536) + (size_t)(b0+m)*1536 + mat*DD + (cb & 7)*64 + lane] = v;
  }
}

// ---------------------------------------------------------------------------
// ATTN: 128 WGs = (b,h). Reduce qkv partials (+bias), write Kc/Vc[p], stage
// K/V rows to LDS, softmax, ctx. h==0 WGs also zero sB for ffn2 atomics.
// ---------------------------------------------------------------------------
__device__ __forceinline__ void attn_stage(const P& prm, int p, int l, float* SH) {
  const int wg = blockIdx.x, t = threadIdx.x;
  if (wg >= 128) return;
  const int b = wg >> 3, h = wg & 7;
  float* QV = SH;            // 64
  float* KN = SH + 64;       // 64
  float* VN = SH + 128;      // 64
  float* LK = SH + 192;      // 32*KLS
  float* LV = LK + 32*KLS;   // 32*KLS
  float* AW = LV + 32*KLS;   // 32

  if (t < 192) {
    int mat = t >> 6, d = t & 63;
    int gc = mat*DD + h*DHH + d;
    float v = prm.qkvp[(size_t)b*1536 + gc] + prm.qkvp[(size_t)BB*1536 + (size_t)b*1536 + gc];
    v += ((mat == 0) ? prm.bq : (mat == 1) ? prm.bk : prm.bv)[l*DD + h*DHH + d];
    if (mat == 0) QV[d] = v;
    else if (mat == 1) { KN[d] = v; prm.Kc[KVIDX(l,b,p) + h*DHH + d] = v; }
    else               { VN[d] = v; prm.Vc[KVIDX(l,b,p) + h*DHH + d] = v; }
  }
  if (h == 0) for (int i = t; i < DD; i += 256) prm.sB[(size_t)b*DD + i] = 0.f;
  __syncthreads();
  for (int idx = t; idx < (p+1)*64; idx += 256) {
    int j = idx >> 6, d = idx & 63;
    LK[j*KLS + d] = (j < p) ? prm.Kc[KVIDX(l,b,j) + h*DHH + d] : KN[d];
    LV[j*KLS + d] = (j < p) ? prm.Vc[KVIDX(l,b,j) + h*DHH + d] : VN[d];
  }
  __syncthreads();
  if (t < 64) {
    int j = t;
    float sc = -1e30f;
    if (j <= p) {
      float s = 0.f;
#pragma unroll 16
      for (int d = 0; d < DHH; d++) s += QV[d] * LK[j*KLS + d];
      sc = s * 0.125f;  // 1/sqrt(64)
    }
    float mx = sc;
#pragma unroll
    for (int m = 32; m >= 1; m >>= 1) mx = fmaxf(mx, __shfl_xor(mx, m));
    float e = (j <= p) ? __expf(sc - mx) : 0.f;
    float den = e;
#pragma unroll
    for (int m = 32; m >= 1; m >>= 1) den += __shfl_xor(den, m);
    if (j < 32) AW[j] = (j <= p) ? (e / den) : 0.f;
  }
  __syncthreads();
  if (t < 64) {
    int d = t;
    float a = 0.f;
    for (int j = 0; j <= p; j++) a += AW[j] * LV[j*KLS + d];
    prm.ctx[(size_t)b*DD + h*DHH + d] = a;
  }
}

// ---------------------------------------------------------------------------
// OPROJ: partials of ctx@Wo -> pg[kg][b][512]. 256 WGs = cb(8) x b(16) x kg(2).
// Also zeroes f1 for ffn1 atomics. Bias/residual folded in ffn1.
// ---------------------------------------------------------------------------
__device__ __forceinline__ void oproj_stage(const P& prm, int l, float* SH) {
  const int wg = blockIdx.x, t = threadIdx.x;
  const int kg = wg & 1, b = (wg >> 1) & 15, cb = wg >> 5;
  float* X   = SH;        // 256
  float* RED = SH + 256;  // 256
  X[t] = prm.ctx[(size_t)b*DD + kg*256 + t];
  if (t < 128) prm.f1[(size_t)wg*128 + t] = 0.f;
  __syncthreads();
  const int w = t >> 6, lane = t & 63;
  const float* wp = prm.Wo + (size_t)l*DD*DD + (size_t)(kg*256 + w*64)*DD + cb*64 + lane;
  float a = 0.f;
  for (int kk = 0; kk < 64; kk += 4) {
    float4 xv = *(const float4*)&X[w*64 + kk];
    float w0 = wp[0], w1 = wp[DD], w2 = wp[2*DD], w3 = wp[3*DD];
    wp += 4*DD;
    a += xv.x*w0 + xv.y*w1 + xv.z*w2 + xv.w*w3;
  }
  RED[w*64 + lane] = a;
  __syncthreads();
  if (t < 64) {
    float v = RED[t] + RED[64 + t] + RED[128 + t] + RED[192 + t];
    prm.pg[(size_t)kg*(BB*DD) + (size_t)b*DD + cb*64 + t] = v;
  }
}

// ---------------------------------------------------------------------------
// FFN1: u = pg0+pg1+xbuf+bo; x=LN1(u); atomic f1 += x@W1 (bias/relu at read).
// 256 WGs = cb(32) x mb(4) x kg(2). cb==0,kg==0 publishes ln1x.
// ---------------------------------------------------------------------------
__device__ __forceinline__ void ffn1_stage(const P& prm, int l, float* SH) {
  const int wg = blockIdx.x, t = threadIdx.x;
  const int kg = wg & 1, mb = (wg >> 1) & 3, cb = wg >> 3;
  const int b0 = mb * 4;
  float* X   = SH;            // 4*XP
  float* RED = SH + 4*XP;     // 1024
  float* MV  = RED + 1024;    // 8
  for (int idx = t; idx < 4*DD; idx += 256) {
    int r = idx >> 9, i = idx & 511;
    float u = prm.pg[(size_t)(b0+r)*DD + i] + prm.pg[(size_t)BB*DD + (size_t)(b0+r)*DD + i]
            + prm.xbuf[(size_t)(b0+r)*DD + i] + prm.bo[l*DD + i];
    X[r*XP + i] = u;
  }
  __syncthreads();
  ln_stats4(X, MV, t);
  __syncthreads();
  const float* g  = prm.ln1s + l*DD;
  const float* be = prm.ln1b + l*DD;
  for (int idx = t; idx < 4*DD; idx += 256) {
    int r = idx >> 9, i = idx & 511;
    X[r*XP + i] = (X[r*XP + i] - MV[r*2]) * MV[r*2+1] * g[i] + be[i];
  }
  __syncthreads();
  if (cb == 0 && kg == 0) {
    for (int idx = t; idx < 4*DD; idx += 256) {
      int r = idx >> 9, i = idx & 511;
      prm.ln1x[(size_t)(b0+r)*DD + i] = X[r*XP + i];
    }
  }
  {
    const int w = t >> 6, lane = t & 63;
    const int k0 = kg*256 + w*64;
    const int c = cb*64 + lane;
    const float* wp = prm.W1 + (size_t)l*DD*DFF + (size_t)k0*DFF + c;
    float a0 = 0.f, a1 = 0.f, a2 = 0.f, a3 = 0.f;
    for (int kk = 0; kk < 64; kk += 4) {
      float4 x0 = *(const float4*)&X[0*XP + k0 + kk];
      float4 x1 = *(const float4*)&X[1*XP + k0 + kk];
      float4 x2 = *(const float4*)&X[2*XP + k0 + kk];
      float4 x3 = *(const float4*)&X[3*XP + k0 + kk];
      float w0 = wp[0], w1 = wp[DFF], w2 = wp[2*DFF], w3 = wp[3*DFF];
      wp += 4*DFF;
      a0 += x0.x*w0 + x0.y*w1 + x0.z*w2 + x0.w*w3;
      a1 += x1.x*w0 + x1.y*w1 + x1.z*w2 + x1.w*w3;
      a2 += x2.x*w0 + x2.y*w1 + x2.z*w2 + x2.w*w3;
      a3 += x3.x*w0 + x3.y*w1 + x3.z*w2 + x3.w*w3;
    }
    RED[w*256 +   0 + lane] = a0;
    RED[w*256 +  64 + lane] = a1;
    RED[w*256 + 128 + lane] = a2;
    RED[w*256 + 192 + lane] = a3;
  }
  __syncthreads();
  {
    int m = t >> 6, lane = t & 63;
    float v = RED[0 + m*64 + lane] + RED[256 + m*64 + lane]
            + RED[512 + m*64 + lane] + RED[768 + m*64 + lane];
    atomicAdd(&prm.f1[(size_t)(b0+m)*DFF + cb*64 + lane], v);
  }
}

// ---------------------------------------------------------------------------
// FFN2: x = relu(f1+b1) slice; atomic sB += x@W2 (+ln1x+b2 by kg==0).
// 256 WGs = cb(8) x mb(4) x kg(8). sB pre-zeroed by attn.
// ---------------------------------------------------------------------------
__device__ __forceinline__ void ffn2_stage(const P& prm, int l, float* SH) {
  const int wg = blockIdx.x, t = threadIdx.x;
  const int kg = wg & 7, mb = (wg >> 3) & 3, cb = wg >> 5;
  const int b0 = mb * 4;
  float* X   = SH;            // 4*XP2
  float* RED = SH + 4*XP2;    // 1024
  for (int idx = t; idx < 4*256; idx += 256) {
    int r = idx >> 8, i = idx & 255;
    X[r*XP2 + i] = fmaxf(prm.f1[(size_t)(b0+r)*DFF + kg*256 + i]
                         + prm.b1[l*DFF + kg*256 + i], 0.f);
  }
  __syncthreads();
  {
    const int w = t >> 6, lane = t & 63;
    const int c = cb*64 + lane;
    const float* wp = prm.W2 + (size_t)l*DFF*DD + (size_t)(kg*256 + w*64)*DD + c;
    float a0 = 0.f, a1 = 0.f, a2 = 0.f, a3 = 0.f;
    for (int kk = 0; kk < 64; kk += 4) {
      float4 x0 = *(const float4*)&X[0*XP2 + w*64 + kk];
      float4 x1 = *(const float4*)&X[1*XP2 + w*64 + kk];
      float4 x2 = *(const float4*)&X[2*XP2 + w*64 + kk];
      float4 x3 = *(const float4*)&X[3*XP2 + w*64 + kk];
      float w0 = wp[0], w1 = wp[DD], w2 = wp[2*DD], w3 = wp[3*DD];
      wp += 4*DD;
      a0 += x0.x*w0 + x0.y*w1 + x0.z*w2 + x0.w*w3;
      a1 += x1.x*w0 + x1.y*w1 + x1.z*w2 + x1.w*w3;
      a2 += x2.x*w0 + x2.y*w1 + x2.z*w2 + x2.w*w3;
      a3 += x3.x*w0 + x3.y*w1 + x3.z*w2 + x3.w*w3;
    }
    RED[w*256 +   0 + lane] = a0;
    RED[w*256 +  64 + lane] = a1;
    RED[w*256 + 128 + lane] = a2;
    RED[w*256 + 192 + lane] = a3;
  }
  __syncthreads();
  {
    int m = t >> 6, lane = t & 63;
    float v = RED[0 + m*64 + lane] + RED[256 + m*64 + lane]
            + RED[512 + m*64 + lane] + RED[768 + m*64 + lane];
    int c = cb*64 + lane;
    if (kg == 0) v += prm.ln1x[(size_t)(b0+m)*DD + c] + prm.b2[l*DD + c];
    atomicAdd(&prm.sB[(size_t)(b0+m)*DD + c], v);
  }
}

// ---------------------------------------------------------------------------
// FINAL: out row 30 = LN2_3(sB)@Wf + bf. 16 WGs, 1 wave each.
// ---------------------------------------------------------------------------
__device__ __forceinline__ void final_stage(const P& prm) {
  const int wg = blockIdx.x, t = threadIdx.x;
  if (wg >= BB || t >= 64) return;
  const int b = wg;
  float v[8];
  float s = 0.f, q = 0.f;
#pragma unroll
  for (int j = 0; j < 8; j++) {
    float x = prm.sB[(size_t)b*DD + t + j*64];
    v[j] = x; s += x; q += x*x;
  }
#pragma unroll
  for (int m = 32; m >= 1; m >>= 1) { s += __shfl_xor(s, m); q += __shfl_xor(q, m); }
  const float mu = s * (1.f/DD);
  const float rs = rsqrtf(fmaxf(q * (1.f/DD) - mu*mu, 0.f) + 1e-5f);
  const float* g  = prm.ln2s + 3*DD;
  const float* be = prm.ln2b + 3*DD;
  float po[8];
#pragma unroll
  for (int oc = 0; oc < 8; oc++) po[oc] = 0.f;
#pragma unroll
  for (int j = 0; j < 8; j++) {
    const int i = t + j*64;
    const float x = (v[j] - mu) * rs * g[i] + be[i];
#pragma unroll
    for (int oc = 0; oc < 8; oc++) po[oc] += x * prm.Wf[i*DOUTC + oc];
  }
#pragma unroll
  for (int m = 32; m >= 1; m >>= 1) {
#pragma unroll
    for (int oc = 0; oc < 8; oc++) po[oc] += __shfl_xor(po[oc], m);
  }
  if (t < 8) prm.out[((size_t)b*TT + 30)*DOUTC + t] = po[t] + prm.bf[t];
}

// ---------------------------------------------------------------------------
__global__ void __launch_bounds__(256, 1) k_all(P prm) {
  __shared__ __align__(16) float SH[4416];   // 17.7 KB
  unsigned tgt = 0;
  for (int p = 0; p < TT; p++) {
    for (int l = 0; l < LLAYERS; l++) {
      proj_stage(prm, p, l, SH);  tgt += NWG; gbar(prm.bar, tgt);
      attn_stage(prm, p, l, SH);  tgt += NWG; gbar(prm.bar, tgt);
      oproj_stage(prm, l, SH);    tgt += NWG; gbar(prm.bar, tgt);
      ffn1_stage(prm, l, SH);     tgt += NWG; gbar(prm.bar, tgt);
      ffn2_stage(prm, l, SH);     tgt += NWG; gbar(prm.bar, tgt);
    }
  }
  final_stage(prm);
}

// ---------------------------------------------------------------------------
extern "C" void kernel_launch(void* const* d_in, const int* in_sizes, int n_in,
                              void* d_out, int out_size, void* d_ws, size_t ws_size,
                              hipStream_t stream) {
  (void)in_sizes; (void)n_in; (void)out_size; (void)ws_size;
  P prm;
  prm.seq  = (const float*)d_in[0];
  prm.pe   = (const float*)d_in[1];
  prm.Wt   = (const float*)d_in[2];
  prm.bt   = (const float*)d_in[3];
  prm.Wq   = (const float*)d_in[4];
  prm.bq   = (const float*)d_in[5];
  prm.Wk   = (const float*)d_in[6];
  prm.bk   = (const float*)d_in[7];
  prm.Wv   = (const float*)d_in[8];
  prm.bv   = (const float*)d_in[9];
  prm.Wo   = (const float*)d_in[10];
  prm.bo   = (const float*)d_in[11];
  prm.ln1s = (const float*)d_in[12];
  prm.ln1b = (const float*)d_in[13];
  prm.W1   = (const float*)d_in[14];
  prm.b1   = (const float*)d_in[15];
  prm.W2   = (const float*)d_in[16];
  prm.b2   = (const float*)d_in[17];
  prm.ln2s = (const float*)d_in[18];
  prm.ln2b = (const float*)d_in[19];
  prm.Wf   = (const float*)d_in[20];
  prm.bf   = (const float*)d_in[21];

  float* ws = (float*)d_ws;
  const size_t KSZ = (size_t)LLAYERS * BB * TT * DD;   // ~1.02M floats
  prm.Kc   = ws;
  prm.Vc   = prm.Kc   + KSZ;
  prm.qkvp = prm.Vc   + KSZ;                 // 2*16*1536 = 49152
  prm.pg   = prm.qkvp + 2*BB*1536;           // 2*16*512  = 16384
  prm.ctx  = prm.pg   + 2*BB*DD;             // 8192
  prm.xbuf = prm.ctx  + BB*DD;               // 8192
  prm.ln1x = prm.xbuf + BB*DD;               // 8192
  prm.sB   = prm.ln1x + BB*DD;               // 8192
  prm.f1   = prm.sB   + BB*DD;               // 32768
  prm.bar  = (unsigned*)(prm.f1 + BB*DFF);
  prm.out  = (float*)d_out;

  hipMemsetAsync((void*)prm.bar, 0, 64, stream);
  hipLaunchKernelGGL(k_all, dim3(NWG), dim3(256), 0, stream, prm);
}